// Round 1
// baseline (678.218 us; speedup 1.0000x reference)
//
#include <hip/hip_runtime.h>

#define D 64

// z = x @ W^T + b  ; 16 rows/block, 256 threads (4 waves x 4 rows), W^T staged in LDS
__global__ __launch_bounds__(256) void gemm_z(const float* __restrict__ x,
                                              const float* __restrict__ W,
                                              const float* __restrict__ b,
                                              float* __restrict__ z, int n) {
    __shared__ float wt[D * D];   // wt[k*64+j] = W[j*64+k]
    __shared__ float xs[16 * D];
    int tid = threadIdx.x;
    for (int i = tid; i < D * D; i += 256) {
        int j = i >> 6, k = i & 63;
        wt[k * D + j] = W[i];
    }
    int row0 = blockIdx.x * 16;
    for (int i = tid; i < 16 * D; i += 256) {
        int r = row0 + (i >> 6);
        xs[i] = (r < n) ? x[(size_t)r * D + (i & 63)] : 0.f;
    }
    __syncthreads();
    int col = tid & 63;
    int w   = tid >> 6;   // wave id 0..3
    float bb = b[col];
    float acc[4];
#pragma unroll
    for (int r = 0; r < 4; ++r) acc[r] = bb;
#pragma unroll
    for (int k = 0; k < D; ++k) {
        float wv = wt[k * D + col];               // 2-way bank alias: free
#pragma unroll
        for (int r = 0; r < 4; ++r)
            acc[r] += xs[(w * 4 + r) * D + k] * wv;  // wave-uniform broadcast
    }
#pragma unroll
    for (int r = 0; r < 4; ++r) {
        int row = row0 + w * 4 + r;
        if (row < n) z[(size_t)row * D + col] = acc[r];
    }
}

// wave-per-edge: e = att . leakyrelu(z[src]+z[dst]); ex = exp(e); ssum[dst] += ex
__global__ __launch_bounds__(256) void edge_scores(const int* __restrict__ src,
                                                   const int* __restrict__ dst,
                                                   const float* __restrict__ z,
                                                   const float* __restrict__ att,
                                                   float* __restrict__ exbuf,
                                                   float* __restrict__ ssum,
                                                   int e_cnt) {
    int lane = threadIdx.x & 63;
    int edge = blockIdx.x * 4 + (threadIdx.x >> 6);
    if (edge >= e_cnt) return;
    int s = src[edge], d = dst[edge];
    float v = z[(size_t)s * D + lane] + z[(size_t)d * D + lane];
    v = v > 0.f ? v : 0.2f * v;
    float p = v * att[lane];
#pragma unroll
    for (int off = 32; off >= 1; off >>= 1)
        p += __shfl_xor(p, off, 64);
    float ex = __expf(p);
    if (lane == 0) {
        exbuf[edge] = ex;
        atomicAdd(&ssum[d], ex);
    }
}

// wave-per-edge: out[dst] += (ex/ssum[dst]) * x[src]
__global__ __launch_bounds__(256) void edge_scatter(const int* __restrict__ src,
                                                    const int* __restrict__ dst,
                                                    const float* __restrict__ x,
                                                    const float* __restrict__ exbuf,
                                                    const float* __restrict__ ssum,
                                                    float* __restrict__ out,
                                                    int e_cnt) {
    int lane = threadIdx.x & 63;
    int edge = blockIdx.x * 4 + (threadIdx.x >> 6);
    if (edge >= e_cnt) return;
    int s = src[edge], d = dst[edge];
    float alpha = exbuf[edge] / ssum[d];
    atomicAdd(&out[(size_t)d * D + lane], alpha * x[(size_t)s * D + lane]);
}

extern "C" void kernel_launch(void* const* d_in, const int* in_sizes, int n_in,
                              void* d_out, int out_size, void* d_ws, size_t ws_size,
                              hipStream_t stream) {
    const float* x   = (const float*)d_in[0];
    const int*   ei  = (const int*)d_in[1];
    const float* W   = (const float*)d_in[2];
    const float* b   = (const float*)d_in[3];
    const float* att = (const float*)d_in[4];
    int n = in_sizes[0] / D;
    int e = in_sizes[1] / 2;
    const int* src = ei;          // edge_index[0]
    const int* dst = ei + e;      // edge_index[1]

    float* z     = (float*)d_ws;                 // N*D
    float* exbuf = z + (size_t)n * D;            // E
    float* ssum  = exbuf + e;                    // N
    float* out   = (float*)d_out;

    hipMemsetAsync(ssum, 0, (size_t)n * sizeof(float), stream);
    hipMemsetAsync(out, 0, (size_t)out_size * sizeof(float), stream);

    gemm_z<<<(n + 15) / 16, 256, 0, stream>>>(x, W, b, z, n);
    edge_scores<<<(e + 3) / 4, 256, 0, stream>>>(src, dst, z, att, exbuf, ssum, e);
    edge_scatter<<<(e + 3) / 4, 256, 0, stream>>>(src, dst, x, exbuf, ssum, out, e);
}

// Round 2
// 651.401 us; speedup vs baseline: 1.0412x; 1.0412x over previous
//
#include <hip/hip_runtime.h>

#define D 64

// z = x @ W^T + b  ; 16 rows/block, 256 threads (4 waves x 4 rows), W^T staged in LDS
__global__ __launch_bounds__(256) void gemm_z(const float* __restrict__ x,
                                              const float* __restrict__ W,
                                              const float* __restrict__ b,
                                              float* __restrict__ z, int n) {
    __shared__ float wt[D * D];   // wt[k*64+j] = W[j*64+k]
    __shared__ float xs[16 * D];
    int tid = threadIdx.x;
    for (int i = tid; i < D * D; i += 256) {
        int j = i >> 6, k = i & 63;
        wt[k * D + j] = W[i];
    }
    int row0 = blockIdx.x * 16;
    for (int i = tid; i < 16 * D; i += 256) {
        int r = row0 + (i >> 6);
        xs[i] = (r < n) ? x[(size_t)r * D + (i & 63)] : 0.f;
    }
    __syncthreads();
    int col = tid & 63;
    int w   = tid >> 6;
    float bb = b[col];
    float acc[4];
#pragma unroll
    for (int r = 0; r < 4; ++r) acc[r] = bb;
#pragma unroll
    for (int k = 0; k < D; ++k) {
        float wv = wt[k * D + col];               // 2-way bank alias: free
#pragma unroll
        for (int r = 0; r < 4; ++r)
            acc[r] += xs[(w * 4 + r) * D + k] * wv;
    }
#pragma unroll
    for (int r = 0; r < 4; ++r) {
        int row = row0 + w * 4 + r;
        if (row < n) z[(size_t)row * D + col] = acc[r];
    }
}

__global__ __launch_bounds__(256) void count_deg(const int* __restrict__ dst,
                                                 int* __restrict__ deg, int e_cnt) {
    int e = blockIdx.x * 256 + threadIdx.x;
    if (e < e_cnt) atomicAdd(&deg[dst[e]], 1);
}

// single-block exclusive scan of deg[0..n) -> rowstart[0..n]
__global__ __launch_bounds__(1024) void scan_deg(const int* __restrict__ deg,
                                                 int* __restrict__ rowstart, int n) {
    __shared__ int part[1024];
    int t = threadIdx.x;
    int chunk = (n + 1023) >> 10;
    int lo = t * chunk, hi = min(lo + chunk, n);
    int s = 0;
    for (int i = lo; i < hi; ++i) s += deg[i];
    part[t] = s;
    __syncthreads();
    for (int off = 1; off < 1024; off <<= 1) {   // Hillis-Steele inclusive
        int v = (t >= off) ? part[t - off] : 0;
        __syncthreads();
        part[t] += v;
        __syncthreads();
    }
    int off = (t > 0) ? part[t - 1] : 0;         // exclusive prefix for this chunk
    for (int i = lo; i < hi; ++i) { rowstart[i] = off; off += deg[i]; }
    if (t == 1023) rowstart[n] = part[1023];
}

// srcids[rowstart[d] + cursor[d]++] = src[e]
__global__ __launch_bounds__(256) void csr_fill(const int* __restrict__ src,
                                                const int* __restrict__ dst,
                                                const int* __restrict__ rowstart,
                                                int* __restrict__ cursor,
                                                int* __restrict__ srcids, int e_cnt) {
    int e = blockIdx.x * 256 + threadIdx.x;
    if (e >= e_cnt) return;
    int d = dst[e];
    int idx = rowstart[d] + atomicAdd(&cursor[d], 1);
    srcids[idx] = src[e];
}

// wave-per-node fused: score + softmax-denominator + weighted sum, no atomics
__global__ __launch_bounds__(256) void gather(const int* __restrict__ srcids,
                                              const int* __restrict__ rowstart,
                                              const float* __restrict__ z,
                                              const float* __restrict__ x,
                                              const float* __restrict__ att,
                                              float* __restrict__ out, int n) {
    int lane = threadIdx.x & 63;
    int node = blockIdx.x * 4 + (threadIdx.x >> 6);
    if (node >= n) return;
    int rs = rowstart[node], re = rowstart[node + 1];
    float zd = z[(size_t)node * D + lane];
    float al = att[lane];
    float acc = 0.f, ssum = 0.f;
    for (int e = rs; e < re; ++e) {
        int sid = srcids[e];                       // wave-uniform broadcast load
        float v = z[(size_t)sid * D + lane] + zd;
        v = v > 0.f ? v : 0.2f * v;
        float p = v * al;
#pragma unroll
        for (int off = 32; off >= 1; off >>= 1)
            p += __shfl_xor(p, off, 64);           // butterfly: all lanes get sum
        float ex = __expf(p);
        ssum += ex;
        acc += ex * x[(size_t)sid * D + lane];
    }
    out[(size_t)node * D + lane] = (re > rs) ? acc / ssum : 0.f;
}

extern "C" void kernel_launch(void* const* d_in, const int* in_sizes, int n_in,
                              void* d_out, int out_size, void* d_ws, size_t ws_size,
                              hipStream_t stream) {
    const float* x   = (const float*)d_in[0];
    const int*   ei  = (const int*)d_in[1];
    const float* W   = (const float*)d_in[2];
    const float* b   = (const float*)d_in[3];
    const float* att = (const float*)d_in[4];
    int n = in_sizes[0] / D;
    int e = in_sizes[1] / 2;
    const int* src = ei;          // edge_index[0]
    const int* dst = ei + e;      // edge_index[1]

    // workspace layout (floats/ints are both 4 B)
    float* z        = (float*)d_ws;                  // N*D
    int*   deg      = (int*)(z + (size_t)n * D);     // N (also reused as cursor)
    int*   rowstart = deg + n;                       // N+1
    int*   srcids   = rowstart + n + 1;              // E
    float* out      = (float*)d_out;

    hipMemsetAsync(deg, 0, (size_t)n * sizeof(int), stream);
    gemm_z<<<(n + 15) / 16, 256, 0, stream>>>(x, W, b, z, n);
    count_deg<<<(e + 255) / 256, 256, 0, stream>>>(dst, deg, e);
    scan_deg<<<1, 1024, 0, stream>>>(deg, rowstart, n);
    hipMemsetAsync(deg, 0, (size_t)n * sizeof(int), stream);   // reuse as cursor
    csr_fill<<<(e + 255) / 256, 256, 0, stream>>>(src, dst, rowstart, deg, srcids, e);
    gather<<<(n + 3) / 4, 256, 0, stream>>>(srcids, rowstart, z, x, att, out, n);
}

// Round 3
// 391.648 us; speedup vs baseline: 1.7317x; 1.6632x over previous
//
#include <hip/hip_runtime.h>

#define D 64

// z = x @ W^T + b written at stride zstride; optionally copy x alongside
// (zx[row*128 + 0..63] = z, zx[row*128 + 64..127] = x)
__global__ __launch_bounds__(256) void gemm_z(const float* __restrict__ x,
                                              const float* __restrict__ W,
                                              const float* __restrict__ b,
                                              float* __restrict__ zout, int n,
                                              int zstride, int copyx) {
    __shared__ float wt[D * D];   // wt[k*64+j] = W[j*64+k]
    __shared__ float xs[16 * D];
    int tid = threadIdx.x;
    for (int i = tid; i < D * D; i += 256) {
        int j = i >> 6, k = i & 63;
        wt[k * D + j] = W[i];
    }
    int row0 = blockIdx.x * 16;
    for (int i = tid; i < 16 * D; i += 256) {
        int r = row0 + (i >> 6);
        xs[i] = (r < n) ? x[(size_t)r * D + (i & 63)] : 0.f;
    }
    __syncthreads();
    int col = tid & 63;
    int w   = tid >> 6;
    float bb = b[col];
    float acc[4];
#pragma unroll
    for (int r = 0; r < 4; ++r) acc[r] = bb;
#pragma unroll
    for (int k = 0; k < D; ++k) {
        float wv = wt[k * D + col];               // 2-way bank alias: free
#pragma unroll
        for (int r = 0; r < 4; ++r)
            acc[r] += xs[(w * 4 + r) * D + k] * wv;
    }
#pragma unroll
    for (int r = 0; r < 4; ++r) {
        int row = row0 + w * 4 + r;
        if (row < n) {
            zout[(size_t)row * zstride + col] = acc[r];
            if (copyx) zout[(size_t)row * zstride + D + col] = xs[(w * 4 + r) * D + col];
        }
    }
}

// deg histogram; optionally capture per-edge slot (order within a node arbitrary but unique)
__global__ __launch_bounds__(256) void count_deg(const int* __restrict__ dst,
                                                 int* __restrict__ deg,
                                                 int* __restrict__ slot, int e_cnt) {
    int e = blockIdx.x * 256 + threadIdx.x;
    if (e >= e_cnt) return;
    int s = atomicAdd(&deg[dst[e]], 1);
    if (slot) slot[e] = s;
}

// ---- 3-phase coalesced scan ----
__global__ __launch_bounds__(256) void scan_part(const int* __restrict__ deg,
                                                 int* __restrict__ part, int n) {
    __shared__ int red[256];
    int t = threadIdx.x;
    int i = blockIdx.x * 256 + t;
    red[t] = (i < n) ? deg[i] : 0;
    __syncthreads();
    for (int off = 128; off >= 1; off >>= 1) {
        if (t < off) red[t] += red[t + off];
        __syncthreads();
    }
    if (t == 0) part[blockIdx.x] = red[0];
}

__global__ __launch_bounds__(512) void scan_top(int* __restrict__ part, int B) {
    __shared__ int s[512];
    int t = threadIdx.x;
    int v = (t < B) ? part[t] : 0;
    s[t] = v;
    __syncthreads();
    for (int off = 1; off < 512; off <<= 1) {
        int u = (t >= off) ? s[t - off] : 0;
        __syncthreads();
        s[t] += u;
        __syncthreads();
    }
    if (t < B) part[t] = s[t] - v;   // exclusive
}

__global__ __launch_bounds__(256) void scan_final(const int* __restrict__ deg,
                                                  const int* __restrict__ part,
                                                  int* __restrict__ rowstart, int n) {
    __shared__ int s[256];
    int t = threadIdx.x;
    int i = blockIdx.x * 256 + t;
    int v = (i < n) ? deg[i] : 0;
    s[t] = v;
    __syncthreads();
    for (int off = 1; off < 256; off <<= 1) {
        int u = (t >= off) ? s[t - off] : 0;
        __syncthreads();
        s[t] += u;
        __syncthreads();
    }
    int incl = s[t] + part[blockIdx.x];
    if (i < n) rowstart[i] = incl - v;       // exclusive
    if (i == n - 1) rowstart[n] = incl;      // total = E
}

// srcids[rowstart[d] + slot[e]] = src[e]   (no atomics)
__global__ __launch_bounds__(256) void csr_fill_slot(const int* __restrict__ src,
                                                     const int* __restrict__ dst,
                                                     const int* __restrict__ rowstart,
                                                     const int* __restrict__ slot,
                                                     int* __restrict__ srcids, int e_cnt) {
    int e = blockIdx.x * 256 + threadIdx.x;
    if (e >= e_cnt) return;
    srcids[rowstart[dst[e]] + slot[e]] = src[e];
}

// fallback: cursor-based fill
__global__ __launch_bounds__(256) void csr_fill_cursor(const int* __restrict__ src,
                                                       const int* __restrict__ dst,
                                                       const int* __restrict__ rowstart,
                                                       int* __restrict__ cursor,
                                                       int* __restrict__ srcids, int e_cnt) {
    int e = blockIdx.x * 256 + threadIdx.x;
    if (e >= e_cnt) return;
    int d = dst[e];
    srcids[rowstart[d] + atomicAdd(&cursor[d], 1)] = src[e];
}

// wave-per-node fused score+softmax+sum; 2-way edge unroll for MLP
__global__ __launch_bounds__(256) void gather(const int* __restrict__ srcids,
                                              const int* __restrict__ rowstart,
                                              const float* __restrict__ zbase, int zstride,
                                              const float* __restrict__ xbase, int xstride,
                                              const float* __restrict__ att,
                                              float* __restrict__ out, int n) {
    int lane = threadIdx.x & 63;
    int node = blockIdx.x * 4 + (threadIdx.x >> 6);
    if (node >= n) return;
    int rs = rowstart[node], re = rowstart[node + 1];
    float zd = zbase[(size_t)node * zstride + lane];
    float al = att[lane];
    float acc = 0.f, ssum = 0.f;
    int e = rs;
    for (; e + 1 < re; e += 2) {
        int s0 = srcids[e], s1 = srcids[e + 1];
        float z0 = zbase[(size_t)s0 * zstride + lane];
        float x0 = xbase[(size_t)s0 * xstride + lane];
        float z1 = zbase[(size_t)s1 * zstride + lane];
        float x1 = xbase[(size_t)s1 * xstride + lane];
        float v0 = z0 + zd; v0 = v0 > 0.f ? v0 : 0.2f * v0;
        float v1 = z1 + zd; v1 = v1 > 0.f ? v1 : 0.2f * v1;
        float p0 = v0 * al, p1 = v1 * al;
#pragma unroll
        for (int off = 32; off >= 1; off >>= 1) {
            p0 += __shfl_xor(p0, off, 64);
            p1 += __shfl_xor(p1, off, 64);
        }
        float e0 = __expf(p0), e1 = __expf(p1);
        ssum += e0 + e1;
        acc += e0 * x0 + e1 * x1;
    }
    if (e < re) {
        int s0 = srcids[e];
        float z0 = zbase[(size_t)s0 * zstride + lane];
        float x0 = xbase[(size_t)s0 * xstride + lane];
        float v0 = z0 + zd; v0 = v0 > 0.f ? v0 : 0.2f * v0;
        float p0 = v0 * al;
#pragma unroll
        for (int off = 32; off >= 1; off >>= 1)
            p0 += __shfl_xor(p0, off, 64);
        float e0 = __expf(p0);
        ssum += e0;
        acc += e0 * x0;
    }
    out[(size_t)node * D + lane] = (re > rs) ? acc / ssum : 0.f;
}

extern "C" void kernel_launch(void* const* d_in, const int* in_sizes, int n_in,
                              void* d_out, int out_size, void* d_ws, size_t ws_size,
                              hipStream_t stream) {
    const float* x   = (const float*)d_in[0];
    const int*   ei  = (const int*)d_in[1];
    const float* W   = (const float*)d_in[2];
    const float* b   = (const float*)d_in[3];
    const float* att = (const float*)d_in[4];
    int n = in_sizes[0] / D;
    int e = in_sizes[1] / 2;
    const int* src = ei;
    const int* dst = ei + e;
    float* out = (float*)d_out;

    int nBlkN = (n + 255) / 256;          // scan partial blocks (<=512 required)
    size_t need_rich = ((size_t)n * 2 * D + n + (n + 1) + (size_t)e * 2 + 512) * 4;

    if (ws_size >= need_rich && nBlkN <= 512) {
        // rich layout: zx[N][128] | deg[N] | rowstart[N+1] | srcids[E] | slot[E] | part[512]
        float* zx       = (float*)d_ws;
        int*   deg      = (int*)(zx + (size_t)n * 2 * D);
        int*   rowstart = deg + n;
        int*   srcids   = rowstart + n + 1;
        int*   slot     = srcids + e;
        int*   part     = slot + e;

        hipMemsetAsync(deg, 0, (size_t)n * sizeof(int), stream);
        gemm_z<<<(n + 15) / 16, 256, 0, stream>>>(x, W, b, zx, n, 2 * D, 1);
        count_deg<<<(e + 255) / 256, 256, 0, stream>>>(dst, deg, slot, e);
        scan_part<<<nBlkN, 256, 0, stream>>>(deg, part, n);
        scan_top<<<1, 512, 0, stream>>>(part, nBlkN);
        scan_final<<<nBlkN, 256, 0, stream>>>(deg, part, rowstart, n);
        csr_fill_slot<<<(e + 255) / 256, 256, 0, stream>>>(src, dst, rowstart, slot, srcids, e);
        gather<<<(n + 3) / 4, 256, 0, stream>>>(srcids, rowstart,
                                                zx, 2 * D, zx + D, 2 * D, att, out, n);
    } else {
        // compact layout: z[N][64] | deg[N] | rowstart[N+1] | srcids[E] | part[512]
        float* z        = (float*)d_ws;
        int*   deg      = (int*)(z + (size_t)n * D);
        int*   rowstart = deg + n;
        int*   srcids   = rowstart + n + 1;
        int*   part     = srcids + e;

        hipMemsetAsync(deg, 0, (size_t)n * sizeof(int), stream);
        gemm_z<<<(n + 15) / 16, 256, 0, stream>>>(x, W, b, z, n, D, 0);
        count_deg<<<(e + 255) / 256, 256, 0, stream>>>(dst, deg, (int*)nullptr, e);
        scan_part<<<nBlkN, 256, 0, stream>>>(deg, part, n);
        scan_top<<<1, 512, 0, stream>>>(part, nBlkN);
        scan_final<<<nBlkN, 256, 0, stream>>>(deg, part, rowstart, n);
        hipMemsetAsync(deg, 0, (size_t)n * sizeof(int), stream);   // reuse as cursor
        csr_fill_cursor<<<(e + 255) / 256, 256, 0, stream>>>(src, dst, rowstart, deg, srcids, e);
        gather<<<(n + 3) / 4, 256, 0, stream>>>(srcids, rowstart,
                                                z, D, x, D, att, out, n);
    }
}

// Round 4
// 379.959 us; speedup vs baseline: 1.7850x; 1.0308x over previous
//
#include <hip/hip_runtime.h>

#define D 64
#define LOG2E 1.4426950408889634f

// z = x @ W^T + b. If interleave: writes zxi[row*128 + 2c] = {z_c, x_c} (float2).
// Else: writes z[row*zstride + c] = z_c.
// 256 threads = 4 waves; 32 rows/block, 8 rows/wave. W^T in LDS with stride 65
// (pad: store bank (k+j)%32, read bank (k+col)%32 -> 2-way alias = free).
__global__ __launch_bounds__(256) void gemm_z(const float* __restrict__ x,
                                              const float* __restrict__ W,
                                              const float* __restrict__ b,
                                              float* __restrict__ zout, int n,
                                              int zstride, int interleave) {
    __shared__ float wt[D * 65];      // wt[k*65 + j] = W[j*D + k]
    __shared__ float xs[32 * D];
    int tid = threadIdx.x;
    for (int i = tid; i < D * D; i += 256) {
        int j = i >> 6, k = i & 63;
        wt[k * 65 + j] = W[i];        // 2-way bank alias: free
    }
    int row0 = blockIdx.x * 32;
    for (int i = tid; i < 32 * D; i += 256) {
        int r = row0 + (i >> 6);
        xs[i] = (r < n) ? x[(size_t)r * D + (i & 63)] : 0.f;
    }
    __syncthreads();
    int col = tid & 63;
    int w   = tid >> 6;               // wave id 0..3 -> rows w*8..w*8+7
    float bb = b[col];
    float acc[8];
#pragma unroll
    for (int r = 0; r < 8; ++r) acc[r] = bb;
#pragma unroll
    for (int k4 = 0; k4 < D; k4 += 4) {
        float wv0 = wt[(k4 + 0) * 65 + col];
        float wv1 = wt[(k4 + 1) * 65 + col];
        float wv2 = wt[(k4 + 2) * 65 + col];
        float wv3 = wt[(k4 + 3) * 65 + col];
#pragma unroll
        for (int r = 0; r < 8; ++r) {
            const float4 xv = *(const float4*)&xs[(w * 8 + r) * D + k4]; // broadcast
            acc[r] += xv.x * wv0 + xv.y * wv1 + xv.z * wv2 + xv.w * wv3;
        }
    }
#pragma unroll
    for (int r = 0; r < 8; ++r) {
        int row = row0 + w * 8 + r;
        if (row < n) {
            if (interleave) {
                float2 v = make_float2(acc[r], xs[(w * 8 + r) * D + col]);
                *(float2*)&zout[(size_t)row * 128 + 2 * col] = v;   // coalesced 8B/lane
            } else {
                zout[(size_t)row * zstride + col] = acc[r];
            }
        }
    }
}

// deg histogram; optionally capture per-edge slot
__global__ __launch_bounds__(256) void count_deg(const int* __restrict__ dst,
                                                 int* __restrict__ deg,
                                                 int* __restrict__ slot, int e_cnt) {
    int e = blockIdx.x * 256 + threadIdx.x;
    if (e >= e_cnt) return;
    int s = atomicAdd(&deg[dst[e]], 1);
    if (slot) slot[e] = s;
}

// ---- 3-phase coalesced scan ----
__global__ __launch_bounds__(256) void scan_part(const int* __restrict__ deg,
                                                 int* __restrict__ part, int n) {
    __shared__ int red[256];
    int t = threadIdx.x;
    int i = blockIdx.x * 256 + t;
    red[t] = (i < n) ? deg[i] : 0;
    __syncthreads();
    for (int off = 128; off >= 1; off >>= 1) {
        if (t < off) red[t] += red[t + off];
        __syncthreads();
    }
    if (t == 0) part[blockIdx.x] = red[0];
}

__global__ __launch_bounds__(512) void scan_top(int* __restrict__ part, int B) {
    __shared__ int s[512];
    int t = threadIdx.x;
    int v = (t < B) ? part[t] : 0;
    s[t] = v;
    __syncthreads();
    for (int off = 1; off < 512; off <<= 1) {
        int u = (t >= off) ? s[t - off] : 0;
        __syncthreads();
        s[t] += u;
        __syncthreads();
    }
    if (t < B) part[t] = s[t] - v;   // exclusive
}

__global__ __launch_bounds__(256) void scan_final(const int* __restrict__ deg,
                                                  const int* __restrict__ part,
                                                  int* __restrict__ rowstart, int n) {
    __shared__ int s[256];
    int t = threadIdx.x;
    int i = blockIdx.x * 256 + t;
    int v = (i < n) ? deg[i] : 0;
    s[t] = v;
    __syncthreads();
    for (int off = 1; off < 256; off <<= 1) {
        int u = (t >= off) ? s[t - off] : 0;
        __syncthreads();
        s[t] += u;
        __syncthreads();
    }
    int incl = s[t] + part[blockIdx.x];
    if (i < n) rowstart[i] = incl - v;
    if (i == n - 1) rowstart[n] = incl;
}

__global__ __launch_bounds__(256) void csr_fill_slot(const int* __restrict__ src,
                                                     const int* __restrict__ dst,
                                                     const int* __restrict__ rowstart,
                                                     const int* __restrict__ slot,
                                                     int* __restrict__ srcids, int e_cnt) {
    int e = blockIdx.x * 256 + threadIdx.x;
    if (e >= e_cnt) return;
    srcids[rowstart[dst[e]] + slot[e]] = src[e];
}

__global__ __launch_bounds__(256) void csr_fill_cursor(const int* __restrict__ src,
                                                       const int* __restrict__ dst,
                                                       const int* __restrict__ rowstart,
                                                       int* __restrict__ cursor,
                                                       int* __restrict__ srcids, int e_cnt) {
    int e = blockIdx.x * 256 + threadIdx.x;
    if (e >= e_cnt) return;
    int d = dst[e];
    srcids[rowstart[d] + atomicAdd(&cursor[d], 1)] = src[e];
}

// wave-per-node, 2 edges/wave (half-wave per edge), 2 dims/lane.
// zxi[row*128 + 2d] = {z_d, x_d}: one coalesced float4/lane covers z AND x.
__global__ __launch_bounds__(256) void gather2(const int* __restrict__ srcids,
                                               const int* __restrict__ rowstart,
                                               const float* __restrict__ zxi,
                                               const float* __restrict__ att,
                                               float* __restrict__ out, int n) {
    int lane = threadIdx.x & 63;
    int node = blockIdx.x * 4 + (threadIdx.x >> 6);
    if (node >= n) return;
    int t = lane & 31;                 // half-lane: dims 2t, 2t+1
    int h = lane >> 5;                 // half id: edge offset
    int rs = rowstart[node], re = rowstart[node + 1];

    const float4 zdv = *(const float4*)(zxi + (size_t)node * 128 + 4 * t);
    float zd0 = zdv.x, zd1 = zdv.z;
    float a0 = att[2 * t] * LOG2E, a1 = att[2 * t + 1] * LOG2E;

    float ax0 = 0.f, ax1 = 0.f, ssum = 0.f;
    for (int e = rs; e < re; e += 2) {
        int eidx = e + h;
        bool live = eidx < re;
        int sid = live ? srcids[eidx] : node;
        const float4 zs = *(const float4*)(zxi + (size_t)sid * 128 + 4 * t);
        float v0 = zs.x + zd0; v0 = v0 > 0.f ? v0 : 0.2f * v0;
        float v1 = zs.z + zd1; v1 = v1 > 0.f ? v1 : 0.2f * v1;
        float p = v0 * a0 + v1 * a1;
#pragma unroll
        for (int off = 16; off >= 1; off >>= 1)
            p += __shfl_xor(p, off, 64);          // per-half sum
        float ex = live ? __builtin_exp2f(p) : 0.f;
        ssum += ex;
        ax0 += ex * zs.y;                          // x[2t]
        ax1 += ex * zs.w;                          // x[2t+1]
    }
    // combine the two halves
    ssum += __shfl_xor(ssum, 32, 64);
    ax0  += __shfl_xor(ax0, 32, 64);
    ax1  += __shfl_xor(ax1, 32, 64);
    if (h == 0) {
        float inv = (re > rs) ? 1.f / ssum : 0.f;
        float2 o = make_float2(ax0 * inv, ax1 * inv);
        *(float2*)&out[(size_t)node * D + 2 * t] = o;   // coalesced 8B/lane
    }
}

// fallback gather (separate z, x arrays)
__global__ __launch_bounds__(256) void gather_plain(const int* __restrict__ srcids,
                                                    const int* __restrict__ rowstart,
                                                    const float* __restrict__ z,
                                                    const float* __restrict__ x,
                                                    const float* __restrict__ att,
                                                    float* __restrict__ out, int n) {
    int lane = threadIdx.x & 63;
    int node = blockIdx.x * 4 + (threadIdx.x >> 6);
    if (node >= n) return;
    int rs = rowstart[node], re = rowstart[node + 1];
    float zd = z[(size_t)node * D + lane];
    float al = att[lane] * LOG2E;
    float acc = 0.f, ssum = 0.f;
    for (int e = rs; e < re; ++e) {
        int sid = srcids[e];
        float v = z[(size_t)sid * D + lane] + zd;
        v = v > 0.f ? v : 0.2f * v;
        float p = v * al;
#pragma unroll
        for (int off = 32; off >= 1; off >>= 1)
            p += __shfl_xor(p, off, 64);
        float ex = __builtin_exp2f(p);
        ssum += ex;
        acc += ex * x[(size_t)sid * D + lane];
    }
    out[(size_t)node * D + lane] = (re > rs) ? acc / ssum : 0.f;
}

extern "C" void kernel_launch(void* const* d_in, const int* in_sizes, int n_in,
                              void* d_out, int out_size, void* d_ws, size_t ws_size,
                              hipStream_t stream) {
    const float* x   = (const float*)d_in[0];
    const int*   ei  = (const int*)d_in[1];
    const float* W   = (const float*)d_in[2];
    const float* b   = (const float*)d_in[3];
    const float* att = (const float*)d_in[4];
    int n = in_sizes[0] / D;
    int e = in_sizes[1] / 2;
    const int* src = ei;
    const int* dst = ei + e;
    float* out = (float*)d_out;

    int nBlkN = (n + 255) / 256;
    size_t need_rich = ((size_t)n * 2 * D + n + (n + 1) + (size_t)e * 2 + 512) * 4;

    if (ws_size >= need_rich && nBlkN <= 512) {
        // rich: zxi[N][128] | deg[N] | rowstart[N+1] | srcids[E] | slot[E] | part[512]
        float* zxi      = (float*)d_ws;
        int*   deg      = (int*)(zxi + (size_t)n * 2 * D);
        int*   rowstart = deg + n;
        int*   srcids   = rowstart + n + 1;
        int*   slot     = srcids + e;
        int*   part     = slot + e;

        hipMemsetAsync(deg, 0, (size_t)n * sizeof(int), stream);
        gemm_z<<<(n + 31) / 32, 256, 0, stream>>>(x, W, b, zxi, n, 128, 1);
        count_deg<<<(e + 255) / 256, 256, 0, stream>>>(dst, deg, slot, e);
        scan_part<<<nBlkN, 256, 0, stream>>>(deg, part, n);
        scan_top<<<1, 512, 0, stream>>>(part, nBlkN);
        scan_final<<<nBlkN, 256, 0, stream>>>(deg, part, rowstart, n);
        csr_fill_slot<<<(e + 255) / 256, 256, 0, stream>>>(src, dst, rowstart, slot, srcids, e);
        gather2<<<(n + 3) / 4, 256, 0, stream>>>(srcids, rowstart, zxi, att, out, n);
    } else {
        // compact: z[N][64] | deg[N] | rowstart[N+1] | srcids[E] | part[512]
        float* z        = (float*)d_ws;
        int*   deg      = (int*)(z + (size_t)n * D);
        int*   rowstart = deg + n;
        int*   srcids   = rowstart + n + 1;
        int*   part     = srcids + e;

        hipMemsetAsync(deg, 0, (size_t)n * sizeof(int), stream);
        gemm_z<<<(n + 31) / 32, 256, 0, stream>>>(x, W, b, z, n, D, 0);
        count_deg<<<(e + 255) / 256, 256, 0, stream>>>(dst, deg, (int*)nullptr, e);
        scan_part<<<nBlkN, 256, 0, stream>>>(deg, part, n);
        scan_top<<<1, 512, 0, stream>>>(part, nBlkN);
        scan_final<<<nBlkN, 256, 0, stream>>>(deg, part, rowstart, n);
        hipMemsetAsync(deg, 0, (size_t)n * sizeof(int), stream);
        csr_fill_cursor<<<(e + 255) / 256, 256, 0, stream>>>(src, dst, rowstart, deg, srcids, e);
        gather_plain<<<(n + 3) / 4, 256, 0, stream>>>(srcids, rowstart, z, x, att, out, n);
    }
}

// Round 5
// 335.690 us; speedup vs baseline: 2.0204x; 1.1319x over previous
//
#include <hip/hip_runtime.h>

#define D 64
#define LOG2E 1.4426950408889634f

// z = x @ W^T + b. Wave-uniform rows: each wave owns 16 rows, lane = col.
// x[row*64+k] is wave-uniform -> scalar loads (s_load) via scalar cache.
// W^T in LDS stride 65 (conflict-free). acc[16] only -> low VGPR, high occupancy.
// interleave: zxi[row*128 + 2c] = {z_c, x_c}; else z[row*64 + c].
__global__ __launch_bounds__(256) void gemm_z(const float* __restrict__ x,
                                              const float* __restrict__ W,
                                              const float* __restrict__ b,
                                              float* __restrict__ zout, int n,
                                              int interleave) {
    const float* xa = (const float*)__builtin_assume_aligned(x, 16);
    __shared__ float wt[D * 65];          // wt[k*65 + j] = W[j*D + k]
    int tid = threadIdx.x;
    for (int i = tid; i < D * D; i += 256) {
        int j = i >> 6, k = i & 63;
        wt[k * 65 + j] = W[i];            // stride-65 store: conflict-free
    }
    __syncthreads();
    int col = tid & 63;
    int w   = tid >> 6;                   // wave 0..3
    int row0 = blockIdx.x * 64 + w * 16;  // 16 rows per wave (wave-uniform)
    float bb = b[col];
    float acc[16];
#pragma unroll
    for (int r = 0; r < 16; ++r) acc[r] = bb;

    for (int k4 = 0; k4 < D; k4 += 4) {   // NOT fully unrolled: keep VGPR low
        float wv0 = wt[(k4 + 0) * 65 + col];
        float wv1 = wt[(k4 + 1) * 65 + col];
        float wv2 = wt[(k4 + 2) * 65 + col];
        float wv3 = wt[(k4 + 3) * 65 + col];
#pragma unroll
        for (int r = 0; r < 16; ++r) {
            int row = row0 + r;
            row = row < n ? row : n - 1;  // wave-uniform clamp (scalar)
            const float* xp = &xa[(size_t)row * D + k4];
            acc[r] += xp[0] * wv0 + xp[1] * wv1 + xp[2] * wv2 + xp[3] * wv3;
        }
    }
#pragma unroll
    for (int r = 0; r < 16; ++r) {
        int row = row0 + r;
        if (row < n) {
            if (interleave) {
                float xv = xa[(size_t)row * D + col];        // coalesced vector load
                float2 v = make_float2(acc[r], xv);
                *(float2*)&zout[(size_t)row * 128 + 2 * col] = v;
            } else {
                zout[(size_t)row * D + col] = acc[r];
            }
        }
    }
}

// deg histogram; optionally capture per-edge slot
__global__ __launch_bounds__(256) void count_deg(const int* __restrict__ dst,
                                                 int* __restrict__ deg,
                                                 int* __restrict__ slot, int e_cnt) {
    int e = blockIdx.x * 256 + threadIdx.x;
    if (e >= e_cnt) return;
    int s = atomicAdd(&deg[dst[e]], 1);
    if (slot) slot[e] = s;
}

// ---- 3-phase coalesced scan ----
__global__ __launch_bounds__(256) void scan_part(const int* __restrict__ deg,
                                                 int* __restrict__ part, int n) {
    __shared__ int red[256];
    int t = threadIdx.x;
    int i = blockIdx.x * 256 + t;
    red[t] = (i < n) ? deg[i] : 0;
    __syncthreads();
    for (int off = 128; off >= 1; off >>= 1) {
        if (t < off) red[t] += red[t + off];
        __syncthreads();
    }
    if (t == 0) part[blockIdx.x] = red[0];
}

__global__ __launch_bounds__(512) void scan_top(int* __restrict__ part, int B) {
    __shared__ int s[512];
    int t = threadIdx.x;
    int v = (t < B) ? part[t] : 0;
    s[t] = v;
    __syncthreads();
    for (int off = 1; off < 512; off <<= 1) {
        int u = (t >= off) ? s[t - off] : 0;
        __syncthreads();
        s[t] += u;
        __syncthreads();
    }
    if (t < B) part[t] = s[t] - v;   // exclusive
}

__global__ __launch_bounds__(256) void scan_final(const int* __restrict__ deg,
                                                  const int* __restrict__ part,
                                                  int* __restrict__ rowstart, int n) {
    __shared__ int s[256];
    int t = threadIdx.x;
    int i = blockIdx.x * 256 + t;
    int v = (i < n) ? deg[i] : 0;
    s[t] = v;
    __syncthreads();
    for (int off = 1; off < 256; off <<= 1) {
        int u = (t >= off) ? s[t - off] : 0;
        __syncthreads();
        s[t] += u;
        __syncthreads();
    }
    int incl = s[t] + part[blockIdx.x];
    if (i < n) rowstart[i] = incl - v;
    if (i == n - 1) rowstart[n] = incl;
}

__global__ __launch_bounds__(256) void csr_fill_slot(const int* __restrict__ src,
                                                     const int* __restrict__ dst,
                                                     const int* __restrict__ rowstart,
                                                     const int* __restrict__ slot,
                                                     int* __restrict__ srcids, int e_cnt) {
    int e = blockIdx.x * 256 + threadIdx.x;
    if (e >= e_cnt) return;
    srcids[rowstart[dst[e]] + slot[e]] = src[e];
}

__global__ __launch_bounds__(256) void csr_fill_cursor(const int* __restrict__ src,
                                                       const int* __restrict__ dst,
                                                       const int* __restrict__ rowstart,
                                                       int* __restrict__ cursor,
                                                       int* __restrict__ srcids, int e_cnt) {
    int e = blockIdx.x * 256 + threadIdx.x;
    if (e >= e_cnt) return;
    int d = dst[e];
    srcids[rowstart[d] + atomicAdd(&cursor[d], 1)] = src[e];
}

// wave-per-node, 4 edges/wave-iter (quarter-wave per edge), 4 dims/lane.
// zxi[row*128 + 2d] = {z_d, x_d}: lane q covers dims 4q..4q+3 via 2 float4 loads.
__global__ __launch_bounds__(256) void gather4(const int* __restrict__ srcids,
                                               const int* __restrict__ rowstart,
                                               const float* __restrict__ zxi,
                                               const float* __restrict__ att,
                                               float* __restrict__ out, int n) {
    int lane = threadIdx.x & 63;
    int node = blockIdx.x * 4 + (threadIdx.x >> 6);
    if (node >= n) return;
    int q = lane & 15;                 // dim group: dims 4q..4q+3
    int h = lane >> 4;                 // edge offset 0..3
    int rs = rowstart[node], re = rowstart[node + 1];

    const float4 zd01 = *(const float4*)(zxi + (size_t)node * 128 + 8 * q);
    const float4 zd23 = *(const float4*)(zxi + (size_t)node * 128 + 8 * q + 4);
    float4 av = *(const float4*)(att + 4 * q);
    float a0 = av.x * LOG2E, a1 = av.y * LOG2E, a2 = av.z * LOG2E, a3 = av.w * LOG2E;

    float ax0 = 0.f, ax1 = 0.f, ax2 = 0.f, ax3 = 0.f, ssum = 0.f;
    for (int e = rs; e < re; e += 4) {
        int eidx = e + h;
        bool live = eidx < re;
        int sid = live ? srcids[eidx] : node;
        const float4 s01 = *(const float4*)(zxi + (size_t)sid * 128 + 8 * q);
        const float4 s23 = *(const float4*)(zxi + (size_t)sid * 128 + 8 * q + 4);
        float v0 = s01.x + zd01.x; v0 = v0 > 0.f ? v0 : 0.2f * v0;
        float v1 = s01.z + zd01.z; v1 = v1 > 0.f ? v1 : 0.2f * v1;
        float v2 = s23.x + zd23.x; v2 = v2 > 0.f ? v2 : 0.2f * v2;
        float v3 = s23.z + zd23.z; v3 = v3 > 0.f ? v3 : 0.2f * v3;
        float p = v0 * a0 + v1 * a1 + v2 * a2 + v3 * a3;
#pragma unroll
        for (int off = 8; off >= 1; off >>= 1)
            p += __shfl_xor(p, off, 64);           // sum within 16-lane group
        float ex = live ? __builtin_exp2f(p) : 0.f;
        ssum += ex;
        ax0 += ex * s01.y;                          // x[4q]
        ax1 += ex * s01.w;                          // x[4q+1]
        ax2 += ex * s23.y;                          // x[4q+2]
        ax3 += ex * s23.w;                          // x[4q+3]
    }
    // combine the 4 edge-groups (they hold identical dim sets)
    ssum += __shfl_xor(ssum, 16, 64); ssum += __shfl_xor(ssum, 32, 64);
    ax0  += __shfl_xor(ax0, 16, 64);  ax0  += __shfl_xor(ax0, 32, 64);
    ax1  += __shfl_xor(ax1, 16, 64);  ax1  += __shfl_xor(ax1, 32, 64);
    ax2  += __shfl_xor(ax2, 16, 64);  ax2  += __shfl_xor(ax2, 32, 64);
    ax3  += __shfl_xor(ax3, 16, 64);  ax3  += __shfl_xor(ax3, 32, 64);
    if (h == 0) {
        float inv = (re > rs) ? 1.f / ssum : 0.f;
        float4 o = make_float4(ax0 * inv, ax1 * inv, ax2 * inv, ax3 * inv);
        *(float4*)&out[(size_t)node * D + 4 * q] = o;   // 16 lanes x 16B coalesced
    }
}

// fallback gather (separate z, x arrays)
__global__ __launch_bounds__(256) void gather_plain(const int* __restrict__ srcids,
                                                    const int* __restrict__ rowstart,
                                                    const float* __restrict__ z,
                                                    const float* __restrict__ x,
                                                    const float* __restrict__ att,
                                                    float* __restrict__ out, int n) {
    int lane = threadIdx.x & 63;
    int node = blockIdx.x * 4 + (threadIdx.x >> 6);
    if (node >= n) return;
    int rs = rowstart[node], re = rowstart[node + 1];
    float zd = z[(size_t)node * D + lane];
    float al = att[lane] * LOG2E;
    float acc = 0.f, ssum = 0.f;
    for (int e = rs; e < re; ++e) {
        int sid = srcids[e];
        float v = z[(size_t)sid * D + lane] + zd;
        v = v > 0.f ? v : 0.2f * v;
        float p = v * al;
#pragma unroll
        for (int off = 32; off >= 1; off >>= 1)
            p += __shfl_xor(p, off, 64);
        float ex = __builtin_exp2f(p);
        ssum += ex;
        acc += ex * x[(size_t)sid * D + lane];
    }
    out[(size_t)node * D + lane] = (re > rs) ? acc / ssum : 0.f;
}

extern "C" void kernel_launch(void* const* d_in, const int* in_sizes, int n_in,
                              void* d_out, int out_size, void* d_ws, size_t ws_size,
                              hipStream_t stream) {
    const float* x   = (const float*)d_in[0];
    const int*   ei  = (const int*)d_in[1];
    const float* W   = (const float*)d_in[2];
    const float* b   = (const float*)d_in[3];
    const float* att = (const float*)d_in[4];
    int n = in_sizes[0] / D;
    int e = in_sizes[1] / 2;
    const int* src = ei;
    const int* dst = ei + e;
    float* out = (float*)d_out;

    int nBlkN = (n + 255) / 256;
    size_t need_rich = ((size_t)n * 2 * D + n + (n + 1) + (size_t)e * 2 + 512) * 4;

    if (ws_size >= need_rich && nBlkN <= 512) {
        // rich: zxi[N][128] | deg[N] | rowstart[N+1] | srcids[E] | slot[E] | part[512]
        float* zxi      = (float*)d_ws;
        int*   deg      = (int*)(zxi + (size_t)n * 2 * D);
        int*   rowstart = deg + n;
        int*   srcids   = rowstart + n + 1;
        int*   slot     = srcids + e;
        int*   part     = slot + e;

        hipMemsetAsync(deg, 0, (size_t)n * sizeof(int), stream);
        gemm_z<<<(n + 63) / 64, 256, 0, stream>>>(x, W, b, zxi, n, 1);
        count_deg<<<(e + 255) / 256, 256, 0, stream>>>(dst, deg, slot, e);
        scan_part<<<nBlkN, 256, 0, stream>>>(deg, part, n);
        scan_top<<<1, 512, 0, stream>>>(part, nBlkN);
        scan_final<<<nBlkN, 256, 0, stream>>>(deg, part, rowstart, n);
        csr_fill_slot<<<(e + 255) / 256, 256, 0, stream>>>(src, dst, rowstart, slot, srcids, e);
        gather4<<<(n + 3) / 4, 256, 0, stream>>>(srcids, rowstart, zxi, att, out, n);
    } else {
        // compact: z[N][64] | deg[N] | rowstart[N+1] | srcids[E] | part[512]
        float* z        = (float*)d_ws;
        int*   deg      = (int*)(z + (size_t)n * D);
        int*   rowstart = deg + n;
        int*   srcids   = rowstart + n + 1;
        int*   part     = srcids + e;

        hipMemsetAsync(deg, 0, (size_t)n * sizeof(int), stream);
        gemm_z<<<(n + 63) / 64, 256, 0, stream>>>(x, W, b, z, n, 0);
        count_deg<<<(e + 255) / 256, 256, 0, stream>>>(dst, deg, (int*)nullptr, e);
        scan_part<<<nBlkN, 256, 0, stream>>>(deg, part, n);
        scan_top<<<1, 512, 0, stream>>>(part, nBlkN);
        scan_final<<<nBlkN, 256, 0, stream>>>(deg, part, rowstart, n);
        hipMemsetAsync(deg, 0, (size_t)n * sizeof(int), stream);
        csr_fill_cursor<<<(e + 255) / 256, 256, 0, stream>>>(src, dst, rowstart, deg, srcids, e);
        gather_plain<<<(n + 3) / 4, 256, 0, stream>>>(srcids, rowstart, z, x, att, out, n);
    }
}

// Round 6
// 288.635 us; speedup vs baseline: 2.3497x; 1.1630x over previous
//
#include <hip/hip_runtime.h>

#define D 64
#define LOG2E 1.4426950408889634f

__device__ __forceinline__ unsigned short f2bf(float f) {      // RNE fp32->bf16
    unsigned int bits = __float_as_uint(f);
    return (unsigned short)((bits + 0x7fffu + ((bits >> 16) & 1u)) >> 16);
}

// z = x @ W^T + b. Wave-uniform rows (16/wave), lane = col; x via scalar loads.
// W^T in LDS stride 65 (conflict-free).
// interleave: zxb[row*64 + c] = uint{ bf16(z_c) | bf16(x_c)<<16 }; else fp32 z.
__global__ __launch_bounds__(256) void gemm_z(const float* __restrict__ x,
                                              const float* __restrict__ W,
                                              const float* __restrict__ b,
                                              float* __restrict__ zout,
                                              unsigned int* __restrict__ zxb,
                                              int n, int interleave) {
    const float* xa = (const float*)__builtin_assume_aligned(x, 16);
    __shared__ float wt[D * 65];          // wt[k*65 + j] = W[j*D + k]
    int tid = threadIdx.x;
    for (int i = tid; i < D * D; i += 256) {
        int j = i >> 6, k = i & 63;
        wt[k * 65 + j] = W[i];
    }
    __syncthreads();
    int col = tid & 63;
    int w   = tid >> 6;
    int row0 = blockIdx.x * 64 + w * 16;  // wave-uniform
    float bb = b[col];
    float acc[16];
#pragma unroll
    for (int r = 0; r < 16; ++r) acc[r] = bb;

    for (int k4 = 0; k4 < D; k4 += 4) {   // not fully unrolled: keep VGPR low
        float wv0 = wt[(k4 + 0) * 65 + col];
        float wv1 = wt[(k4 + 1) * 65 + col];
        float wv2 = wt[(k4 + 2) * 65 + col];
        float wv3 = wt[(k4 + 3) * 65 + col];
#pragma unroll
        for (int r = 0; r < 16; ++r) {
            int row = row0 + r;
            row = row < n ? row : n - 1;  // wave-uniform clamp
            const float* xp = &xa[(size_t)row * D + k4];
            acc[r] += xp[0] * wv0 + xp[1] * wv1 + xp[2] * wv2 + xp[3] * wv3;
        }
    }
#pragma unroll
    for (int r = 0; r < 16; ++r) {
        int row = row0 + r;
        if (row < n) {
            if (interleave) {
                float xv = xa[(size_t)row * D + col];
                unsigned int u = (unsigned int)f2bf(acc[r]) |
                                 ((unsigned int)f2bf(xv) << 16);
                zxb[(size_t)row * 64 + col] = u;     // coalesced 4B/lane
            } else {
                zout[(size_t)row * D + col] = acc[r];
            }
        }
    }
}

__global__ __launch_bounds__(256) void count_deg(const int* __restrict__ dst,
                                                 int* __restrict__ deg,
                                                 int* __restrict__ slot, int e_cnt) {
    int e = blockIdx.x * 256 + threadIdx.x;
    if (e >= e_cnt) return;
    int s = atomicAdd(&deg[dst[e]], 1);
    if (slot) slot[e] = s;
}

// ---- 3-phase coalesced scan ----
__global__ __launch_bounds__(256) void scan_part(const int* __restrict__ deg,
                                                 int* __restrict__ part, int n) {
    __shared__ int red[256];
    int t = threadIdx.x;
    int i = blockIdx.x * 256 + t;
    red[t] = (i < n) ? deg[i] : 0;
    __syncthreads();
    for (int off = 128; off >= 1; off >>= 1) {
        if (t < off) red[t] += red[t + off];
        __syncthreads();
    }
    if (t == 0) part[blockIdx.x] = red[0];
}

__global__ __launch_bounds__(512) void scan_top(int* __restrict__ part, int B) {
    __shared__ int s[512];
    int t = threadIdx.x;
    int v = (t < B) ? part[t] : 0;
    s[t] = v;
    __syncthreads();
    for (int off = 1; off < 512; off <<= 1) {
        int u = (t >= off) ? s[t - off] : 0;
        __syncthreads();
        s[t] += u;
        __syncthreads();
    }
    if (t < B) part[t] = s[t] - v;   // exclusive
}

__global__ __launch_bounds__(256) void scan_final(const int* __restrict__ deg,
                                                  const int* __restrict__ part,
                                                  int* __restrict__ rowstart, int n) {
    __shared__ int s[256];
    int t = threadIdx.x;
    int i = blockIdx.x * 256 + t;
    int v = (i < n) ? deg[i] : 0;
    s[t] = v;
    __syncthreads();
    for (int off = 1; off < 256; off <<= 1) {
        int u = (t >= off) ? s[t - off] : 0;
        __syncthreads();
        s[t] += u;
        __syncthreads();
    }
    int incl = s[t] + part[blockIdx.x];
    if (i < n) rowstart[i] = incl - v;
    if (i == n - 1) rowstart[n] = incl;
}

__global__ __launch_bounds__(256) void csr_fill_slot(const int* __restrict__ src,
                                                     const int* __restrict__ dst,
                                                     const int* __restrict__ rowstart,
                                                     const int* __restrict__ slot,
                                                     int* __restrict__ srcids, int e_cnt) {
    int e = blockIdx.x * 256 + threadIdx.x;
    if (e >= e_cnt) return;
    srcids[rowstart[dst[e]] + slot[e]] = src[e];
}

__global__ __launch_bounds__(256) void csr_fill_cursor(const int* __restrict__ src,
                                                       const int* __restrict__ dst,
                                                       const int* __restrict__ rowstart,
                                                       int* __restrict__ cursor,
                                                       int* __restrict__ srcids, int e_cnt) {
    int e = blockIdx.x * 256 + threadIdx.x;
    if (e >= e_cnt) return;
    int d = dst[e];
    srcids[rowstart[d] + atomicAdd(&cursor[d], 1)] = src[e];
}

// wave-per-node, quarter-wave per edge, 8 edges/iter (2x unroll).
// bf16-packed row: zxb[row*64 + d] = { bf16 z_d | bf16 x_d << 16 }, 256 B/row.
// Lane q (0..15) loads uint4 = dims 4q..4q+3 of one edge: ONE load per edge.
__global__ __launch_bounds__(256) void gather4b(const int* __restrict__ srcids,
                                                const int* __restrict__ rowstart,
                                                const unsigned int* __restrict__ zxb,
                                                const float* __restrict__ att,
                                                float* __restrict__ out, int n) {
    int lane = threadIdx.x & 63;
    int node = blockIdx.x * 4 + (threadIdx.x >> 6);
    if (node >= n) return;
    int q = lane & 15;                 // dim group: 4q..4q+3
    int h = lane >> 4;                 // edge slot 0..3
    int rs = rowstart[node], re = rowstart[node + 1];

    const uint4 zdv = *(const uint4*)(zxb + (size_t)node * 64 + 4 * q);
    float zd0 = __uint_as_float(zdv.x << 16);
    float zd1 = __uint_as_float(zdv.y << 16);
    float zd2 = __uint_as_float(zdv.z << 16);
    float zd3 = __uint_as_float(zdv.w << 16);
    float4 av = *(const float4*)(att + 4 * q);
    float a0 = av.x * LOG2E, a1 = av.y * LOG2E, a2 = av.z * LOG2E, a3 = av.w * LOG2E;

    float ax0 = 0.f, ax1 = 0.f, ax2 = 0.f, ax3 = 0.f, ssum = 0.f;
    for (int e = rs; e < re; e += 8) {
        int e0i = e + h, e1i = e + 4 + h;
        bool l0 = e0i < re, l1 = e1i < re;
        int s0 = l0 ? srcids[e0i] : node;
        int s1 = l1 ? srcids[e1i] : node;
        const uint4 r0 = *(const uint4*)(zxb + (size_t)s0 * 64 + 4 * q);
        const uint4 r1 = *(const uint4*)(zxb + (size_t)s1 * 64 + 4 * q);

        float v0 = __uint_as_float(r0.x << 16) + zd0; v0 = v0 > 0.f ? v0 : 0.2f * v0;
        float v1 = __uint_as_float(r0.y << 16) + zd1; v1 = v1 > 0.f ? v1 : 0.2f * v1;
        float v2 = __uint_as_float(r0.z << 16) + zd2; v2 = v2 > 0.f ? v2 : 0.2f * v2;
        float v3 = __uint_as_float(r0.w << 16) + zd3; v3 = v3 > 0.f ? v3 : 0.2f * v3;
        float p0 = v0 * a0 + v1 * a1 + v2 * a2 + v3 * a3;

        float u0 = __uint_as_float(r1.x << 16) + zd0; u0 = u0 > 0.f ? u0 : 0.2f * u0;
        float u1 = __uint_as_float(r1.y << 16) + zd1; u1 = u1 > 0.f ? u1 : 0.2f * u1;
        float u2 = __uint_as_float(r1.z << 16) + zd2; u2 = u2 > 0.f ? u2 : 0.2f * u2;
        float u3 = __uint_as_float(r1.w << 16) + zd3; u3 = u3 > 0.f ? u3 : 0.2f * u3;
        float p1 = u0 * a0 + u1 * a1 + u2 * a2 + u3 * a3;

#pragma unroll
        for (int off = 8; off >= 1; off >>= 1) {
            p0 += __shfl_xor(p0, off, 64);
            p1 += __shfl_xor(p1, off, 64);
        }
        float ex0 = l0 ? __builtin_exp2f(p0) : 0.f;
        float ex1 = l1 ? __builtin_exp2f(p1) : 0.f;
        ssum += ex0 + ex1;
        ax0 += ex0 * __uint_as_float(r0.x & 0xffff0000u)
             + ex1 * __uint_as_float(r1.x & 0xffff0000u);
        ax1 += ex0 * __uint_as_float(r0.y & 0xffff0000u)
             + ex1 * __uint_as_float(r1.y & 0xffff0000u);
        ax2 += ex0 * __uint_as_float(r0.z & 0xffff0000u)
             + ex1 * __uint_as_float(r1.z & 0xffff0000u);
        ax3 += ex0 * __uint_as_float(r0.w & 0xffff0000u)
             + ex1 * __uint_as_float(r1.w & 0xffff0000u);
    }
    // combine the 4 edge-slots (identical dim sets)
    ssum += __shfl_xor(ssum, 16, 64); ssum += __shfl_xor(ssum, 32, 64);
    ax0  += __shfl_xor(ax0, 16, 64);  ax0  += __shfl_xor(ax0, 32, 64);
    ax1  += __shfl_xor(ax1, 16, 64);  ax1  += __shfl_xor(ax1, 32, 64);
    ax2  += __shfl_xor(ax2, 16, 64);  ax2  += __shfl_xor(ax2, 32, 64);
    ax3  += __shfl_xor(ax3, 16, 64);  ax3  += __shfl_xor(ax3, 32, 64);
    if (h == 0) {
        float inv = (re > rs) ? 1.f / ssum : 0.f;
        float4 o = make_float4(ax0 * inv, ax1 * inv, ax2 * inv, ax3 * inv);
        *(float4*)&out[(size_t)node * D + 4 * q] = o;
    }
}

// fallback gather (fp32, separate z / x)
__global__ __launch_bounds__(256) void gather_plain(const int* __restrict__ srcids,
                                                    const int* __restrict__ rowstart,
                                                    const float* __restrict__ z,
                                                    const float* __restrict__ x,
                                                    const float* __restrict__ att,
                                                    float* __restrict__ out, int n) {
    int lane = threadIdx.x & 63;
    int node = blockIdx.x * 4 + (threadIdx.x >> 6);
    if (node >= n) return;
    int rs = rowstart[node], re = rowstart[node + 1];
    float zd = z[(size_t)node * D + lane];
    float al = att[lane] * LOG2E;
    float acc = 0.f, ssum = 0.f;
    for (int e = rs; e < re; ++e) {
        int sid = srcids[e];
        float v = z[(size_t)sid * D + lane] + zd;
        v = v > 0.f ? v : 0.2f * v;
        float p = v * al;
#pragma unroll
        for (int off = 32; off >= 1; off >>= 1)
            p += __shfl_xor(p, off, 64);
        float ex = __builtin_exp2f(p);
        ssum += ex;
        acc += ex * x[(size_t)sid * D + lane];
    }
    out[(size_t)node * D + lane] = (re > rs) ? acc / ssum : 0.f;
}

extern "C" void kernel_launch(void* const* d_in, const int* in_sizes, int n_in,
                              void* d_out, int out_size, void* d_ws, size_t ws_size,
                              hipStream_t stream) {
    const float* x   = (const float*)d_in[0];
    const int*   ei  = (const int*)d_in[1];
    const float* W   = (const float*)d_in[2];
    const float* b   = (const float*)d_in[3];
    const float* att = (const float*)d_in[4];
    int n = in_sizes[0] / D;
    int e = in_sizes[1] / 2;
    const int* src = ei;
    const int* dst = ei + e;
    float* out = (float*)d_out;

    int nBlkN = (n + 255) / 256;
    size_t need_rich = ((size_t)n * 64 + n + (n + 1) + (size_t)e * 2 + 512) * 4;

    if (ws_size >= need_rich && nBlkN <= 512) {
        // rich: zxb[N*64 uint] | deg[N] | rowstart[N+1] | srcids[E] | slot[E] | part[512]
        unsigned int* zxb = (unsigned int*)d_ws;
        int* deg      = (int*)(zxb + (size_t)n * 64);
        int* rowstart = deg + n;
        int* srcids   = rowstart + n + 1;
        int* slot     = srcids + e;
        int* part     = slot + e;

        hipMemsetAsync(deg, 0, (size_t)n * sizeof(int), stream);
        gemm_z<<<(n + 63) / 64, 256, 0, stream>>>(x, W, b, nullptr, zxb, n, 1);
        count_deg<<<(e + 255) / 256, 256, 0, stream>>>(dst, deg, slot, e);
        scan_part<<<nBlkN, 256, 0, stream>>>(deg, part, n);
        scan_top<<<1, 512, 0, stream>>>(part, nBlkN);
        scan_final<<<nBlkN, 256, 0, stream>>>(deg, part, rowstart, n);
        csr_fill_slot<<<(e + 255) / 256, 256, 0, stream>>>(src, dst, rowstart, slot, srcids, e);
        gather4b<<<(n + 3) / 4, 256, 0, stream>>>(srcids, rowstart, zxb, att, out, n);
    } else {
        // compact fp32 fallback
        float* z        = (float*)d_ws;
        int*   deg      = (int*)(z + (size_t)n * D);
        int*   rowstart = deg + n;
        int*   srcids   = rowstart + n + 1;
        int*   part     = srcids + e;

        hipMemsetAsync(deg, 0, (size_t)n * sizeof(int), stream);
        gemm_z<<<(n + 63) / 64, 256, 0, stream>>>(x, W, b, z, nullptr, n, 0);
        count_deg<<<(e + 255) / 256, 256, 0, stream>>>(dst, deg, (int*)nullptr, e);
        scan_part<<<nBlkN, 256, 0, stream>>>(deg, part, n);
        scan_top<<<1, 512, 0, stream>>>(part, nBlkN);
        scan_final<<<nBlkN, 256, 0, stream>>>(deg, part, rowstart, n);
        hipMemsetAsync(deg, 0, (size_t)n * sizeof(int), stream);
        csr_fill_cursor<<<(e + 255) / 256, 256, 0, stream>>>(src, dst, rowstart, deg, srcids, e);
        gather_plain<<<(n + 3) / 4, 256, 0, stream>>>(srcids, rowstart, z, x, att, out, n);
    }
}

// Round 7
// 240.531 us; speedup vs baseline: 2.8197x; 1.2000x over previous
//
#include <hip/hip_runtime.h>

#define D 64
#define LOG2E 1.4426950408889634f

__device__ __forceinline__ unsigned short f2bf(float f) {      // RNE fp32->bf16
    unsigned int bits = __float_as_uint(f);
    return (unsigned short)((bits + 0x7fffu + ((bits >> 16) & 1u)) >> 16);
}

// z = x @ W^T + b. 64 rows/block in LDS (coalesced float4 staging); wave owns
// 16 rows, lane = col. W^T in LDS stride 65 (conflict-free); xs reads are
// same-address wave broadcasts (free). k-loop rolled -> VGPR ~40.
// interleave: zxb[row*64+c] = uint{bf16(z_c) | bf16(x_c)<<16}; else fp32 z.
__global__ __launch_bounds__(256) void gemm_z(const float* __restrict__ x,
                                              const float* __restrict__ W,
                                              const float* __restrict__ b,
                                              float* __restrict__ zout,
                                              unsigned int* __restrict__ zxb,
                                              int n, int interleave) {
    __shared__ float wt[D * 65];   // wt[k*65+j] = W[j*D+k]
    __shared__ float xs[64 * D];   // 64 staged rows
    int tid = threadIdx.x;
    for (int i = tid; i < D * D; i += 256) {
        int j = i >> 6, k = i & 63;
        wt[k * 65 + j] = W[i];
    }
    int row0 = blockIdx.x * 64;
    for (int i = tid; i < 64 * D / 4; i += 256) {      // 4 float4 per thread
        int r = row0 + (i >> 4);
        float4 v = (r < n) ? ((const float4*)x)[(size_t)r * 16 + (i & 15)]
                           : make_float4(0.f, 0.f, 0.f, 0.f);
        ((float4*)xs)[i] = v;
    }
    __syncthreads();
    int col = tid & 63;
    int w   = tid >> 6;
    float bb = b[col];
    float acc[16];
#pragma unroll
    for (int r = 0; r < 16; ++r) acc[r] = bb;

    for (int k4 = 0; k4 < D; k4 += 4) {    // rolled on purpose: keep VGPR low
        float wv0 = wt[(k4 + 0) * 65 + col];
        float wv1 = wt[(k4 + 1) * 65 + col];
        float wv2 = wt[(k4 + 2) * 65 + col];
        float wv3 = wt[(k4 + 3) * 65 + col];
#pragma unroll
        for (int r = 0; r < 16; ++r) {
            const float4 xv = *(const float4*)&xs[(w * 16 + r) * D + k4];  // broadcast
            acc[r] += xv.x * wv0 + xv.y * wv1 + xv.z * wv2 + xv.w * wv3;
        }
    }
#pragma unroll
    for (int r = 0; r < 16; ++r) {
        int row = row0 + w * 16 + r;
        if (row < n) {
            if (interleave) {
                float xv = xs[(w * 16 + r) * D + col];        // conflict-free
                unsigned int u = (unsigned int)f2bf(acc[r]) |
                                 ((unsigned int)f2bf(xv) << 16);
                zxb[(size_t)row * 64 + col] = u;              // coalesced 4B/lane
            } else {
                zout[(size_t)row * D + col] = acc[r];
            }
        }
    }
}

__global__ __launch_bounds__(256) void count_deg(const int* __restrict__ dst,
                                                 int* __restrict__ deg,
                                                 int* __restrict__ slot, int e_cnt) {
    int e = blockIdx.x * 256 + threadIdx.x;
    if (e >= e_cnt) return;
    int s = atomicAdd(&deg[dst[e]], 1);
    if (slot) slot[e] = s;
}

// ---- 3-phase coalesced scan ----
__global__ __launch_bounds__(256) void scan_part(const int* __restrict__ deg,
                                                 int* __restrict__ part, int n) {
    __shared__ int red[256];
    int t = threadIdx.x;
    int i = blockIdx.x * 256 + t;
    red[t] = (i < n) ? deg[i] : 0;
    __syncthreads();
    for (int off = 128; off >= 1; off >>= 1) {
        if (t < off) red[t] += red[t + off];
        __syncthreads();
    }
    if (t == 0) part[blockIdx.x] = red[0];
}

__global__ __launch_bounds__(512) void scan_top(int* __restrict__ part, int B) {
    __shared__ int s[512];
    int t = threadIdx.x;
    int v = (t < B) ? part[t] : 0;
    s[t] = v;
    __syncthreads();
    for (int off = 1; off < 512; off <<= 1) {
        int u = (t >= off) ? s[t - off] : 0;
        __syncthreads();
        s[t] += u;
        __syncthreads();
    }
    if (t < B) part[t] = s[t] - v;   // exclusive
}

__global__ __launch_bounds__(256) void scan_final(const int* __restrict__ deg,
                                                  const int* __restrict__ part,
                                                  int* __restrict__ rowstart, int n) {
    __shared__ int s[256];
    int t = threadIdx.x;
    int i = blockIdx.x * 256 + t;
    int v = (i < n) ? deg[i] : 0;
    s[t] = v;
    __syncthreads();
    for (int off = 1; off < 256; off <<= 1) {
        int u = (t >= off) ? s[t - off] : 0;
        __syncthreads();
        s[t] += u;
        __syncthreads();
    }
    int incl = s[t] + part[blockIdx.x];
    if (i < n) rowstart[i] = incl - v;
    if (i == n - 1) rowstart[n] = incl;
}

__global__ __launch_bounds__(256) void csr_fill_slot(const int* __restrict__ src,
                                                     const int* __restrict__ dst,
                                                     const int* __restrict__ rowstart,
                                                     const int* __restrict__ slot,
                                                     int* __restrict__ srcids, int e_cnt) {
    int e = blockIdx.x * 256 + threadIdx.x;
    if (e >= e_cnt) return;
    srcids[rowstart[dst[e]] + slot[e]] = src[e];
}

__global__ __launch_bounds__(256) void csr_fill_cursor(const int* __restrict__ src,
                                                       const int* __restrict__ dst,
                                                       const int* __restrict__ rowstart,
                                                       int* __restrict__ cursor,
                                                       int* __restrict__ srcids, int e_cnt) {
    int e = blockIdx.x * 256 + threadIdx.x;
    if (e >= e_cnt) return;
    int d = dst[e];
    srcids[rowstart[d] + atomicAdd(&cursor[d], 1)] = src[e];
}

// wave-per-node, quarter-wave per edge, 8 edges/iter (2x unroll).
// bf16-packed row: zxb[row*64 + d] = { bf16 z_d | bf16 x_d << 16 }, 256 B/row.
__global__ __launch_bounds__(256) void gather4b(const int* __restrict__ srcids,
                                                const int* __restrict__ rowstart,
                                                const unsigned int* __restrict__ zxb,
                                                const float* __restrict__ att,
                                                float* __restrict__ out, int n) {
    int lane = threadIdx.x & 63;
    int node = blockIdx.x * 4 + (threadIdx.x >> 6);
    if (node >= n) return;
    int q = lane & 15;                 // dim group: 4q..4q+3
    int h = lane >> 4;                 // edge slot 0..3
    int rs = rowstart[node], re = rowstart[node + 1];

    const uint4 zdv = *(const uint4*)(zxb + (size_t)node * 64 + 4 * q);
    float zd0 = __uint_as_float(zdv.x << 16);
    float zd1 = __uint_as_float(zdv.y << 16);
    float zd2 = __uint_as_float(zdv.z << 16);
    float zd3 = __uint_as_float(zdv.w << 16);
    float4 av = *(const float4*)(att + 4 * q);
    float a0 = av.x * LOG2E, a1 = av.y * LOG2E, a2 = av.z * LOG2E, a3 = av.w * LOG2E;

    float ax0 = 0.f, ax1 = 0.f, ax2 = 0.f, ax3 = 0.f, ssum = 0.f;
    for (int e = rs; e < re; e += 8) {
        int e0i = e + h, e1i = e + 4 + h;
        bool l0 = e0i < re, l1 = e1i < re;
        int s0 = l0 ? srcids[e0i] : node;
        int s1 = l1 ? srcids[e1i] : node;
        const uint4 r0 = *(const uint4*)(zxb + (size_t)s0 * 64 + 4 * q);
        const uint4 r1 = *(const uint4*)(zxb + (size_t)s1 * 64 + 4 * q);

        float v0 = __uint_as_float(r0.x << 16) + zd0; v0 = v0 > 0.f ? v0 : 0.2f * v0;
        float v1 = __uint_as_float(r0.y << 16) + zd1; v1 = v1 > 0.f ? v1 : 0.2f * v1;
        float v2 = __uint_as_float(r0.z << 16) + zd2; v2 = v2 > 0.f ? v2 : 0.2f * v2;
        float v3 = __uint_as_float(r0.w << 16) + zd3; v3 = v3 > 0.f ? v3 : 0.2f * v3;
        float p0 = v0 * a0 + v1 * a1 + v2 * a2 + v3 * a3;

        float u0 = __uint_as_float(r1.x << 16) + zd0; u0 = u0 > 0.f ? u0 : 0.2f * u0;
        float u1 = __uint_as_float(r1.y << 16) + zd1; u1 = u1 > 0.f ? u1 : 0.2f * u1;
        float u2 = __uint_as_float(r1.z << 16) + zd2; u2 = u2 > 0.f ? u2 : 0.2f * u2;
        float u3 = __uint_as_float(r1.w << 16) + zd3; u3 = u3 > 0.f ? u3 : 0.2f * u3;
        float p1 = u0 * a0 + u1 * a1 + u2 * a2 + u3 * a3;

#pragma unroll
        for (int off = 8; off >= 1; off >>= 1) {
            p0 += __shfl_xor(p0, off, 64);
            p1 += __shfl_xor(p1, off, 64);
        }
        float ex0 = l0 ? __builtin_exp2f(p0) : 0.f;
        float ex1 = l1 ? __builtin_exp2f(p1) : 0.f;
        ssum += ex0 + ex1;
        ax0 += ex0 * __uint_as_float(r0.x & 0xffff0000u)
             + ex1 * __uint_as_float(r1.x & 0xffff0000u);
        ax1 += ex0 * __uint_as_float(r0.y & 0xffff0000u)
             + ex1 * __uint_as_float(r1.y & 0xffff0000u);
        ax2 += ex0 * __uint_as_float(r0.z & 0xffff0000u)
             + ex1 * __uint_as_float(r1.z & 0xffff0000u);
        ax3 += ex0 * __uint_as_float(r0.w & 0xffff0000u)
             + ex1 * __uint_as_float(r1.w & 0xffff0000u);
    }
    ssum += __shfl_xor(ssum, 16, 64); ssum += __shfl_xor(ssum, 32, 64);
    ax0  += __shfl_xor(ax0, 16, 64);  ax0  += __shfl_xor(ax0, 32, 64);
    ax1  += __shfl_xor(ax1, 16, 64);  ax1  += __shfl_xor(ax1, 32, 64);
    ax2  += __shfl_xor(ax2, 16, 64);  ax2  += __shfl_xor(ax2, 32, 64);
    ax3  += __shfl_xor(ax3, 16, 64);  ax3  += __shfl_xor(ax3, 32, 64);
    if (h == 0) {
        float inv = (re > rs) ? 1.f / ssum : 0.f;
        float4 o = make_float4(ax0 * inv, ax1 * inv, ax2 * inv, ax3 * inv);
        *(float4*)&out[(size_t)node * D + 4 * q] = o;
    }
}

// fallback gather (fp32, separate z / x)
__global__ __launch_bounds__(256) void gather_plain(const int* __restrict__ srcids,
                                                    const int* __restrict__ rowstart,
                                                    const float* __restrict__ z,
                                                    const float* __restrict__ x,
                                                    const float* __restrict__ att,
                                                    float* __restrict__ out, int n) {
    int lane = threadIdx.x & 63;
    int node = blockIdx.x * 4 + (threadIdx.x >> 6);
    if (node >= n) return;
    int rs = rowstart[node], re = rowstart[node + 1];
    float zd = z[(size_t)node * D + lane];
    float al = att[lane] * LOG2E;
    float acc = 0.f, ssum = 0.f;
    for (int e = rs; e < re; ++e) {
        int sid = srcids[e];
        float v = z[(size_t)sid * D + lane] + zd;
        v = v > 0.f ? v : 0.2f * v;
        float p = v * al;
#pragma unroll
        for (int off = 32; off >= 1; off >>= 1)
            p += __shfl_xor(p, off, 64);
        float ex = __builtin_exp2f(p);
        ssum += ex;
        acc += ex * x[(size_t)sid * D + lane];
    }
    out[(size_t)node * D + lane] = (re > rs) ? acc / ssum : 0.f;
}

extern "C" void kernel_launch(void* const* d_in, const int* in_sizes, int n_in,
                              void* d_out, int out_size, void* d_ws, size_t ws_size,
                              hipStream_t stream) {
    const float* x   = (const float*)d_in[0];
    const int*   ei  = (const int*)d_in[1];
    const float* W   = (const float*)d_in[2];
    const float* b   = (const float*)d_in[3];
    const float* att = (const float*)d_in[4];
    int n = in_sizes[0] / D;
    int e = in_sizes[1] / 2;
    const int* src = ei;
    const int* dst = ei + e;
    float* out = (float*)d_out;

    int nBlkN = (n + 255) / 256;
    size_t need_rich = ((size_t)n * 64 + n + (n + 1) + (size_t)e * 2 + 512) * 4;

    if (ws_size >= need_rich && nBlkN <= 512) {
        // rich: zxb[N*64 uint] | deg[N] | rowstart[N+1] | srcids[E] | slot[E] | part[512]
        unsigned int* zxb = (unsigned int*)d_ws;
        int* deg      = (int*)(zxb + (size_t)n * 64);
        int* rowstart = deg + n;
        int* srcids   = rowstart + n + 1;
        int* slot     = srcids + e;
        int* part     = slot + e;

        hipMemsetAsync(deg, 0, (size_t)n * sizeof(int), stream);
        gemm_z<<<(n + 63) / 64, 256, 0, stream>>>(x, W, b, nullptr, zxb, n, 1);
        count_deg<<<(e + 255) / 256, 256, 0, stream>>>(dst, deg, slot, e);
        scan_part<<<nBlkN, 256, 0, stream>>>(deg, part, n);
        scan_top<<<1, 512, 0, stream>>>(part, nBlkN);
        scan_final<<<nBlkN, 256, 0, stream>>>(deg, part, rowstart, n);
        csr_fill_slot<<<(e + 255) / 256, 256, 0, stream>>>(src, dst, rowstart, slot, srcids, e);
        gather4b<<<(n + 3) / 4, 256, 0, stream>>>(srcids, rowstart, zxb, att, out, n);
    } else {
        // compact fp32 fallback
        float* z        = (float*)d_ws;
        int*   deg      = (int*)(z + (size_t)n * D);
        int*   rowstart = deg + n;
        int*   srcids   = rowstart + n + 1;
        int*   part     = srcids + e;

        hipMemsetAsync(deg, 0, (size_t)n * sizeof(int), stream);
        gemm_z<<<(n + 63) / 64, 256, 0, stream>>>(x, W, b, z, nullptr, n, 0);
        count_deg<<<(e + 255) / 256, 256, 0, stream>>>(dst, deg, (int*)nullptr, e);
        scan_part<<<nBlkN, 256, 0, stream>>>(deg, part, n);
        scan_top<<<1, 512, 0, stream>>>(part, nBlkN);
        scan_final<<<nBlkN, 256, 0, stream>>>(deg, part, rowstart, n);
        hipMemsetAsync(deg, 0, (size_t)n * sizeof(int), stream);
        csr_fill_cursor<<<(e + 255) / 256, 256, 0, stream>>>(src, dst, rowstart, deg, srcids, e);
        gather_plain<<<(n + 3) / 4, 256, 0, stream>>>(srcids, rowstart, z, x, att, out, n);
    }
}